// Round 10
// baseline (655.615 us; speedup 1.0000x reference)
//
#include <hip/hip_runtime.h>
#include <hip/hip_bf16.h>

using bf16 = __hip_bfloat16;
using short8 = __attribute__((ext_vector_type(8))) short;
using sh4 = __attribute__((ext_vector_type(4))) short;
using f32x4 = __attribute__((ext_vector_type(4))) float;

// Pre-packed A-operand (weights) in MFMA 16x16x32 frag order, module-scope.
// L1 (div path): k = kt*32+(lane>>4)*8+j -> chunk=k/8, c=k%8.
// L2/L3 (chunk-padded path): kt = chunk*SUBT+cc, c = cc*32+(lane>>4)*8+j,
//   weight nonzero iff c < CIN  (tail B reads are clamped in-bounds x zero A).
__device__ __align__(16) bf16 g_wp1[16 * 3 * 512];    //  48 KB (M 256, KT 3)
__device__ __align__(16) bf16 g_wp2[32 * 63 * 512];   // 2.1 MB (M 512, KT 63 = 9*7)
__device__ __align__(16) bf16 g_wp3[64 * 117 * 512];  // 7.7 MB (M 1024, KT 117 = 9*13)
__device__ __align__(16) bf16 g_wp4[1 * 225 * 512];   // 231 KB (M 16, KT 225 exact)

// ---------------- weight packs ----------------
__global__ __launch_bounds__(256) void k_pack1(const float* __restrict__ w) {
  int el = blockIdx.x * 256 + threadIdx.x;
  if (el >= 16 * 3 * 512) return;
  int j = el & 7, lane = (el >> 3) & 63, rest = el >> 9;
  int kt = rest % 3, mt = rest / 3;
  int m = mt * 16 + (lane & 15);
  int k = kt * 32 + ((lane >> 4) * 8) + j;
  int chunk = k >> 3, c = k & 7;
  float val = 0.f;
  if (m < 200 && chunk < 9 && c < 3) val = w[((size_t)m * 3 + c) * 9 + chunk];
  g_wp1[el] = __float2bfloat16(val);
}
template <int CIN, int SUBT, int COUT>
__device__ __forceinline__ void pack_pad(const float* __restrict__ w,
                                         bf16* __restrict__ dst, int total) {
  int el = blockIdx.x * 256 + threadIdx.x;
  if (el >= total) return;
  int j = el & 7, lane = (el >> 3) & 63, rest = el >> 9;
  int kt = rest % (9 * SUBT), mt = rest / (9 * SUBT);
  int chunk = kt / SUBT, cc = kt - chunk * SUBT;
  int m = mt * 16 + (lane & 15);
  int c = cc * 32 + ((lane >> 4) * 8) + j;
  float val = 0.f;
  if (m < COUT && c < CIN) val = w[((size_t)m * CIN + c) * 9 + chunk];
  dst[el] = __float2bfloat16(val);
}
__global__ __launch_bounds__(256) void k_pack2(const float* __restrict__ w) {
  pack_pad<200, 7, 400>(w, g_wp2, 32 * 63 * 512);
}
__global__ __launch_bounds__(256) void k_pack3(const float* __restrict__ w) {
  pack_pad<400, 13, 800>(w, g_wp3, 64 * 117 * 512);
}
__global__ __launch_bounds__(256) void k_pack4(const float* __restrict__ w) {
  pack_pad<800, 25, 10>(w, g_wp4, 225 * 512);
}

// zero-fill xt (pad channels 3..7 must be 0)
__global__ __launch_bounds__(256) void k_fill_xt(float* __restrict__ p, int n4) {
  int i = blockIdx.x * 256 + threadIdx.x;
  if (i < n4) reinterpret_cast<float4*>(p)[i] = float4{0.f, 0.f, 0.f, 0.f};
}
// zero-fill d_out (conv4m accumulates with atomics)
__global__ __launch_bounds__(256) void k_zero_out(float* __restrict__ p) {
  int i = blockIdx.x * 256 + threadIdx.x;
  if (i < 64 * 10 * 13 * 13) p[i] = 0.f;
}

// x: [64][3][132][132] fp32 -> xt: [132*132][64][8] bf16 (c innermost, 8-pad)
__global__ __launch_bounds__(256) void k_transpose_x(const float* __restrict__ x,
                                                     bf16* __restrict__ xt) {
  int idx = blockIdx.x * 256 + threadIdx.x;
  constexpr int N = 64 * 3 * 132 * 132;
  if (idx >= N) return;
  int w = idx % 132;
  int t = idx / 132;
  int h = t % 132;
  t /= 132;
  int c = t % 3;
  int b = t / 3;
  xt[((size_t)(h * 132 + w) * 64 + b) * 8 + c] = __float2bfloat16(x[idx]);
}

// ---------------- L1: division-path sconv (CINW=8 -> shifts) ----------------
template <int CINW, int COUT, int WIN, int OW, int KTILES, int MT, int NPOS, int STRIPE>
__device__ __forceinline__ void sconv_body_div(
    const bf16* __restrict__ in_t, const bf16* __restrict__ wp,
    const float* __restrict__ bias, const int* __restrict__ selh,
    const int* __restrict__ selw, const int* __restrict__ mask,
    bf16* __restrict__ out_t) {
  const int bid = blockIdx.x;
  const int pos = (bid & 7) * STRIPE + (bid >> 3);
  if (pos >= NPOS) return;
  const int tid = threadIdx.x;
  const int lane = tid & 63;
  const int wv = tid >> 6;
  const int nl = lane & 15;
  const int q = lane >> 4;
  const int mt0 = blockIdx.y * (4 * MT) + wv * MT;
  f32x4 acc[MT][4] = {};
  if (mask[pos] != 0) {
    const int y = pos / OW, xq = pos % OW;
    const int ph = selh[pos] + 2 * y;
    const int pw = selw[pos] + 2 * xq;
    const short8* ap = reinterpret_cast<const short8*>(wp);
#pragma unroll
    for (int kt = 0; kt < KTILES; ++kt) {
      int k = kt * 32 + q * 8;
      int chunk = (int)((unsigned)k / (unsigned)CINW);
      int c = k - chunk * CINW;
      if (chunk > 8) { chunk = 8; c = 0; }
      const int di = (chunk * 342) >> 10;
      const int dj = chunk - di * 3;
      const bf16* bp =
          in_t + ((size_t)((ph + di) * WIN + (pw + dj)) * 64 + nl) * CINW + c;
      short8 Bf[4];
#pragma unroll
      for (int t = 0; t < 4; ++t)
        Bf[t] = *reinterpret_cast<const short8*>(bp + (size_t)t * 16 * CINW);
      short8 Af[MT];
#pragma unroll
      for (int ms = 0; ms < MT; ++ms)
        Af[ms] = ap[((size_t)(mt0 + ms) * KTILES + kt) * 64 + lane];
#pragma unroll
      for (int ms = 0; ms < MT; ++ms)
#pragma unroll
        for (int t = 0; t < 4; ++t)
          acc[ms][t] =
              __builtin_amdgcn_mfma_f32_16x16x32_bf16(Af[ms], Bf[t], acc[ms][t], 0, 0, 0);
    }
  }
  const int rowb = q * 4;
#pragma unroll
  for (int ms = 0; ms < MT; ++ms) {
    const int mb = (mt0 + ms) * 16 + rowb;
    if (mb < COUT) {
      const float4 bv = *reinterpret_cast<const float4*>(bias + mb);
#pragma unroll
      for (int t = 0; t < 4; ++t) {
        const int n = t * 16 + nl;
        sh4 s;
#pragma unroll
        for (int r = 0; r < 4; ++r) {
          float vv = acc[ms][t][r] + ((const float*)&bv)[r];
          vv = vv > 0.f ? vv : 0.f;
          bf16 h = __float2bfloat16(vv);
          s[r] = *reinterpret_cast<short*>(&h);
        }
        *reinterpret_cast<sh4*>(out_t + ((size_t)pos * 64 + n) * COUT + mb) = s;
      }
    }
  }
}

// ------------- L2/L3: chunk-outer sconv, software-pipelined ------------------
// Depth-2 prefetch for B (L3 ~400-500cyc), depth-1 for A (L2-hot). Per iter
// issue order: A(next) FIRST, then B(next2) -> the vmcnt wait before the MFMAs
// (which needs A of the current step) leaves the B-prefetch queue in flight.
template <int CIN, int SUBT, int COUT, int WIN, int OW, int MT, int NPOS, int STRIPE>
__device__ __forceinline__ void sconv_body_pad(
    const bf16* __restrict__ in_t, const bf16* __restrict__ wp,
    const float* __restrict__ bias, const int* __restrict__ selh,
    const int* __restrict__ selw, const int* __restrict__ mask,
    bf16* __restrict__ out_t) {
  constexpr int KTILES = 9 * SUBT;
  const int bid = blockIdx.x;
  const int pos = (bid & 7) * STRIPE + (bid >> 3);
  if (pos >= NPOS) return;
  const int tid = threadIdx.x;
  const int lane = tid & 63;
  const int wv = tid >> 6;
  const int nl = lane & 15;
  const int q = lane >> 4;
  const int mt0 = blockIdx.y * (4 * MT) + wv * MT;
  f32x4 acc[MT][4] = {};
  if (mask[pos] != 0) {
    const int y = pos / OW, xq = pos % OW;
    const int ph = selh[pos] + 2 * y;
    const int pw = selw[pos] + 2 * xq;
    const int qoff = q * 8;
    const short8* ap = reinterpret_cast<const short8*>(wp);
    auto cellp = [&](int ch) {
      int di = (ch * 342) >> 10;  // ch/3 for 0..8
      int dj = ch - di * 3;
      return in_t + ((size_t)((ph + di) * WIN + (pw + dj)) * 64 + nl) * CIN;
    };
    const bf16* cell_c = cellp(0);
    const bf16* cell_n = cellp(1);
    short8 B0[4], B1[4], Ac[MT];
    // preload: B(0), B(1), A(0)   (offsets: cc*32+qoff, no tail at cc<2)
#pragma unroll
    for (int ms = 0; ms < MT; ++ms)
      Ac[ms] = ap[((size_t)(mt0 + ms) * KTILES) * 64 + lane];
#pragma unroll
    for (int t = 0; t < 4; ++t)
      B0[t] = *reinterpret_cast<const short8*>(cell_c + qoff + (size_t)t * 16 * CIN);
#pragma unroll
    for (int t = 0; t < 4; ++t)
      B1[t] = *reinterpret_cast<const short8*>(cell_c + 32 + qoff + (size_t)t * 16 * CIN);
    for (int chunk = 0; chunk < 9; ++chunk) {
      const int kbase = chunk * SUBT;
#pragma unroll
      for (int cc = 0; cc < SUBT; ++cc) {
        // A for k-step+1 (issue FIRST)
        const int an = (kbase + cc + 1 < KTILES) ? (kbase + cc + 1) : (KTILES - 1);
        short8 An[MT];
#pragma unroll
        for (int ms = 0; ms < MT; ++ms)
          An[ms] = ap[((size_t)(mt0 + ms) * KTILES + an) * 64 + lane];
        // B for k-step+2
        short8 B2[4];
        {
          const bool same = (cc + 2 < SUBT);
          const bf16* nb = same ? cell_c : cell_n;
          const int ncc = same ? cc + 2 : cc + 2 - SUBT;  // compile-time in unroll
          int noff = ncc * 32 + qoff;
          if (ncc * 32 + 32 > CIN) noff = noff > (CIN - 8) ? (CIN - 8) : noff;
#pragma unroll
          for (int t = 0; t < 4; ++t)
            B2[t] = *reinterpret_cast<const short8*>(nb + noff + (size_t)t * 16 * CIN);
        }
        // MFMAs on current step
#pragma unroll
        for (int ms = 0; ms < MT; ++ms)
#pragma unroll
          for (int t = 0; t < 4; ++t)
            acc[ms][t] = __builtin_amdgcn_mfma_f32_16x16x32_bf16(Ac[ms], B0[t],
                                                                 acc[ms][t], 0, 0, 0);
        // rotate
#pragma unroll
        for (int t = 0; t < 4; ++t) { B0[t] = B1[t]; B1[t] = B2[t]; }
#pragma unroll
        for (int ms = 0; ms < MT; ++ms) Ac[ms] = An[ms];
      }
      cell_c = cell_n;
      cell_n = cellp(chunk + 2 <= 8 ? chunk + 2 : 8);
    }
  }
  const int rowb = q * 4;
#pragma unroll
  for (int ms = 0; ms < MT; ++ms) {
    const int mb = (mt0 + ms) * 16 + rowb;
    if (mb < COUT) {
      const float4 bv = *reinterpret_cast<const float4*>(bias + mb);
#pragma unroll
      for (int t = 0; t < 4; ++t) {
        const int n = t * 16 + nl;
        sh4 s;
#pragma unroll
        for (int r = 0; r < 4; ++r) {
          float vv = acc[ms][t][r] + ((const float*)&bv)[r];
          vv = vv > 0.f ? vv : 0.f;
          bf16 h = __float2bfloat16(vv);
          s[r] = *reinterpret_cast<short*>(&h);
        }
        *reinterpret_cast<sh4*>(out_t + ((size_t)pos * 64 + n) * COUT + mb) = s;
      }
    }
  }
}

__global__ __launch_bounds__(256) void k_sconv1(
    const bf16* __restrict__ in_t, const float* __restrict__ bias,
    const int* __restrict__ selh, const int* __restrict__ selw,
    const int* __restrict__ mask, bf16* __restrict__ out_t) {
  sconv_body_div<8, 200, 132, 65, 3, 4, 4225, 529>(in_t, g_wp1, bias, selh, selw, mask,
                                                   out_t);
}
__global__ __launch_bounds__(256) void k_sconv2(
    const bf16* __restrict__ in_t, const float* __restrict__ bias,
    const int* __restrict__ selh, const int* __restrict__ selw,
    const int* __restrict__ mask, bf16* __restrict__ out_t) {
  sconv_body_pad<200, 7, 400, 65, 31, 4, 961, 121>(in_t, g_wp2, bias, selh, selw, mask,
                                                   out_t);
}
__global__ __launch_bounds__(256) void k_sconv3(
    const bf16* __restrict__ in_t, const float* __restrict__ bias,
    const int* __restrict__ selh, const int* __restrict__ selw,
    const int* __restrict__ mask, bf16* __restrict__ out_t) {
  sconv_body_pad<400, 13, 800, 31, 15, 4, 225, 29>(in_t, g_wp3, bias, selh, selw, mask,
                                                   out_t);
}

// ---------------- L4: dense 3x3 VALID conv via MFMA, 16-way K-split ---------
// grid (169, 4); kslice = gy*4+wv in [0,16); kt = kslice, kslice+16, ...
// Block LDS-reduces its 4 waves, then atomicAdd into zero-initialized d_out.
// gy==0 adds the bias.
__global__ __launch_bounds__(256) void k_conv4m(
    const bf16* __restrict__ in_t,   // [15*15][64][800] bf16
    const float* __restrict__ bias,  // [10] fp32
    float* __restrict__ out) {       // [64][10][13][13] fp32 (pre-zeroed)
  const int pos = blockIdx.x;        // 13*13
  const int y = pos / 13, x = pos % 13;
  const int tid = threadIdx.x;
  const int lane = tid & 63;
  const int wv = tid >> 6;
  const int nl = lane & 15;
  const int q = lane >> 4;
  const int kslice = blockIdx.y * 4 + wv;
  __shared__ f32x4 Racc[4][4][64];
  f32x4 acc[4] = {};
  const short8* ap = reinterpret_cast<const short8*>(g_wp4);
  for (int kt = kslice; kt < 225; kt += 16) {
    const int chunk = kt / 25;  // wave-uniform
    const int c0 = (kt - chunk * 25) * 32;
    const int di = chunk / 3, dj = chunk - di * 3;
    const bf16* bp =
        in_t + ((size_t)((y + di) * 15 + (x + dj)) * 64 + nl) * 800 + c0 + q * 8;
    short8 A0 = ap[(size_t)kt * 64 + lane];
    short8 Bf[4];
#pragma unroll
    for (int t = 0; t < 4; ++t)
      Bf[t] = *reinterpret_cast<const short8*>(bp + (size_t)t * 16 * 800);
#pragma unroll
    for (int t = 0; t < 4; ++t)
      acc[t] = __builtin_amdgcn_mfma_f32_16x16x32_bf16(A0, Bf[t], acc[t], 0, 0, 0);
  }
#pragma unroll
  for (int t = 0; t < 4; ++t) Racc[wv][t][lane] = acc[t];
  __syncthreads();
  if (wv == 0) {
    const int rowb = q * 4;
#pragma unroll
    for (int t = 0; t < 4; ++t) {
      f32x4 s = Racc[0][t][lane];
#pragma unroll
      for (int w2 = 1; w2 < 4; ++w2) {
        f32x4 o = Racc[w2][t][lane];
#pragma unroll
        for (int r = 0; r < 4; ++r) s[r] += o[r];
      }
      const int n = t * 16 + nl;
#pragma unroll
      for (int r = 0; r < 4; ++r) {
        const int m = rowb + r;
        if (m < 10) {
          float v = s[r] + (blockIdx.y == 0 ? bias[m] : 0.f);
          atomicAdd(&out[(((size_t)n * 10 + m) * 13 + y) * 13 + x], v);
        }
      }
    }
  }
}

extern "C" void kernel_launch(void* const* d_in, const int* in_sizes, int n_in,
                              void* d_out, int out_size, void* d_ws, size_t ws_size,
                              hipStream_t stream) {
  const float* x  = (const float*)d_in[0];
  const float* w1 = (const float*)d_in[1];
  const float* b1 = (const float*)d_in[2];
  const float* w2 = (const float*)d_in[3];
  const float* b2 = (const float*)d_in[4];
  const float* w3 = (const float*)d_in[5];
  const float* b3 = (const float*)d_in[6];
  const float* w4 = (const float*)d_in[7];
  const float* b4 = (const float*)d_in[8];
  const int* selh1 = (const int*)d_in[9];
  const int* selw1 = (const int*)d_in[10];
  const int* mask1 = (const int*)d_in[11];
  const int* selh2 = (const int*)d_in[12];
  const int* selw2 = (const int*)d_in[13];
  const int* mask2 = (const int*)d_in[14];
  const int* selh3 = (const int*)d_in[15];
  const int* selw3 = (const int*)d_in[16];
  const int* mask3 = (const int*)d_in[17];

  // ws layout (bytes), total == round-5-proven 157,363,200:
  //   o1t bf16 [65*65][64][200] @ 0            (108,160,000 B; L1 w .. L2 r)
  //   xt  bf16 [132*132][64][8] @ 108,160,000  (17,842,176 B;  fill .. L1 r)
  //   o2t bf16 [31*31][64][400] @ 108,160,000  (49,203,200 B;  L2 w .. L3 r; xt dead)
  //   o3t bf16 [15*15][64][800] @ 0            (23,040,000 B;  L3 w .. L4 r; o1t dead)
  char* ws = (char*)d_ws;
  bf16* o1t = (bf16*)(ws);
  bf16* xt  = (bf16*)(ws + 108160000);
  bf16* o2t = (bf16*)(ws + 108160000);
  bf16* o3t = (bf16*)(ws);

  k_pack1<<<dim3((16 * 3 * 512 + 255) / 256), dim3(256), 0, stream>>>(w1);
  k_pack2<<<dim3((32 * 63 * 512 + 255) / 256), dim3(256), 0, stream>>>(w2);
  k_pack3<<<dim3((64 * 117 * 512 + 255) / 256), dim3(256), 0, stream>>>(w3);
  k_pack4<<<dim3((225 * 512 + 255) / 256), dim3(256), 0, stream>>>(w4);
  k_fill_xt<<<dim3((2230272 + 255) / 256), dim3(256), 0, stream>>>((float*)xt, 2230272);
  k_transpose_x<<<dim3((64 * 3 * 132 * 132 + 255) / 256), dim3(256), 0, stream>>>(x, xt);
  k_zero_out<<<dim3((64 * 10 * 13 * 13 + 255) / 256), dim3(256), 0, stream>>>(
      (float*)d_out);

  // L1: M-pad 256, grid (529*8, 1)
  k_sconv1<<<dim3(529 * 8, 1), dim3(256), 0, stream>>>(xt, b1, selh1, selw1, mask1, o1t);
  // L2: M-pad 512, grid (121*8, 2)
  k_sconv2<<<dim3(121 * 8, 2), dim3(256), 0, stream>>>(o1t, b2, selh2, selw2, mask2, o2t);
  // L3: M-pad 1024, grid (29*8, 4)
  k_sconv3<<<dim3(29 * 8, 4), dim3(256), 0, stream>>>(o2t, b3, selh3, selw3, mask3, o3t);
  // L4: 16-way K-split, atomic accumulate
  k_conv4m<<<dim3(13 * 13, 4), dim3(256), 0, stream>>>(o3t, b4, (float*)d_out);
}

// Round 11
// 651.944 us; speedup vs baseline: 1.0056x; 1.0056x over previous
//
#include <hip/hip_runtime.h>
#include <hip/hip_bf16.h>

using bf16 = __hip_bfloat16;
using short8 = __attribute__((ext_vector_type(8))) short;
using sh4 = __attribute__((ext_vector_type(4))) short;
using f32x4 = __attribute__((ext_vector_type(4))) float;

// Pre-packed A-operand (weights) in MFMA 16x16x32 frag order, module-scope.
// L1 (div path): k = kt*32+(lane>>4)*8+j -> chunk=k/8, c=k%8.
// L2/L3 (chunk-padded path): kt = chunk*SUBT+cc, c = cc*32+(lane>>4)*8+j,
//   weight nonzero iff c < CIN  (tail B reads are clamped in-bounds x zero A).
__device__ __align__(16) bf16 g_wp1[16 * 3 * 512];    //  48 KB (M 256, KT 3)
__device__ __align__(16) bf16 g_wp2[32 * 63 * 512];   // 2.1 MB (M 512, KT 63 = 9*7)
__device__ __align__(16) bf16 g_wp3[64 * 117 * 512];  // 7.7 MB (M 1024, KT 117 = 9*13)
__device__ __align__(16) bf16 g_wp4[1 * 225 * 512];   // 231 KB (M 16, KT 225 exact)

// Compacted masked-on position lists (rebuilt every launch; zero d_ws impact).
__device__ int g_list1[4225];
__device__ int g_list2[961];
__device__ int g_list3[225];
__device__ int g_cnt[3];

// ---------------- weight packs ----------------
__global__ __launch_bounds__(256) void k_pack1(const float* __restrict__ w) {
  int el = blockIdx.x * 256 + threadIdx.x;
  if (el >= 16 * 3 * 512) return;
  int j = el & 7, lane = (el >> 3) & 63, rest = el >> 9;
  int kt = rest % 3, mt = rest / 3;
  int m = mt * 16 + (lane & 15);
  int k = kt * 32 + ((lane >> 4) * 8) + j;
  int chunk = k >> 3, c = k & 7;
  float val = 0.f;
  if (m < 200 && chunk < 9 && c < 3) val = w[((size_t)m * 3 + c) * 9 + chunk];
  g_wp1[el] = __float2bfloat16(val);
}
template <int CIN, int SUBT, int COUT>
__device__ __forceinline__ void pack_pad(const float* __restrict__ w,
                                         bf16* __restrict__ dst, int total) {
  int el = blockIdx.x * 256 + threadIdx.x;
  if (el >= total) return;
  int j = el & 7, lane = (el >> 3) & 63, rest = el >> 9;
  int kt = rest % (9 * SUBT), mt = rest / (9 * SUBT);
  int chunk = kt / SUBT, cc = kt - chunk * SUBT;
  int m = mt * 16 + (lane & 15);
  int c = cc * 32 + ((lane >> 4) * 8) + j;
  float val = 0.f;
  if (m < COUT && c < CIN) val = w[((size_t)m * CIN + c) * 9 + chunk];
  dst[el] = __float2bfloat16(val);
}
__global__ __launch_bounds__(256) void k_pack2(const float* __restrict__ w) {
  pack_pad<200, 7, 400>(w, g_wp2, 32 * 63 * 512);
}
__global__ __launch_bounds__(256) void k_pack3(const float* __restrict__ w) {
  pack_pad<400, 13, 800>(w, g_wp3, 64 * 117 * 512);
}
__global__ __launch_bounds__(256) void k_pack4(const float* __restrict__ w) {
  pack_pad<800, 25, 10>(w, g_wp4, 225 * 512);
}

// ---------------- mask compaction (order irrelevant: disjoint writes) -------
__global__ __launch_bounds__(256) void k_compact(const int* __restrict__ m1,
                                                 const int* __restrict__ m2,
                                                 const int* __restrict__ m3) {
  const int which = blockIdx.x;
  const int* m = which == 0 ? m1 : (which == 1 ? m2 : m3);
  int* lst = which == 0 ? g_list1 : (which == 1 ? g_list2 : g_list3);
  const int n = which == 0 ? 4225 : (which == 1 ? 961 : 225);
  __shared__ int cnt;
  if (threadIdx.x == 0) cnt = 0;
  __syncthreads();
  for (int i = threadIdx.x; i < n; i += 256)
    if (m[i] != 0) lst[atomicAdd(&cnt, 1)] = i;
  __syncthreads();
  if (threadIdx.x == 0) g_cnt[which] = cnt;
}

// Fill masked-OFF positions with relu(bias) (reference: where(mask,conv,0)+bias).
template <int COUT>
__global__ __launch_bounds__(256) void k_fill_off(const int* __restrict__ mask,
                                                  const float* __restrict__ bias,
                                                  bf16* __restrict__ out_t) {
  const int pos = blockIdx.x;
  if (mask[pos] != 0) return;
  bf16* base = out_t + (size_t)pos * 64 * COUT;
  for (int idx = threadIdx.x; idx < 64 * COUT / 8; idx += 256) {
    const int c0 = (idx * 8) % COUT;
    short8 s;
#pragma unroll
    for (int j = 0; j < 8; ++j) {
      float v = bias[c0 + j];
      v = v > 0.f ? v : 0.f;
      bf16 h = __float2bfloat16(v);
      s[j] = *reinterpret_cast<short*>(&h);
    }
    *reinterpret_cast<short8*>(base + (size_t)idx * 8) = s;
  }
}

// zero-fill xt (pad channels 3..7 must be 0)
__global__ __launch_bounds__(256) void k_fill_xt(float* __restrict__ p, int n4) {
  int i = blockIdx.x * 256 + threadIdx.x;
  if (i < n4) reinterpret_cast<float4*>(p)[i] = float4{0.f, 0.f, 0.f, 0.f};
}
// zero-fill d_out (conv4m accumulates with atomics)
__global__ __launch_bounds__(256) void k_zero_out(float* __restrict__ p) {
  int i = blockIdx.x * 256 + threadIdx.x;
  if (i < 64 * 10 * 13 * 13) p[i] = 0.f;
}

// x: [64][3][132][132] fp32 -> xt: [132*132][64][8] bf16 (c innermost, 8-pad)
__global__ __launch_bounds__(256) void k_transpose_x(const float* __restrict__ x,
                                                     bf16* __restrict__ xt) {
  int idx = blockIdx.x * 256 + threadIdx.x;
  constexpr int N = 64 * 3 * 132 * 132;
  if (idx >= N) return;
  int w = idx % 132;
  int t = idx / 132;
  int h = t % 132;
  t /= 132;
  int c = t % 3;
  int b = t / 3;
  xt[((size_t)(h * 132 + w) * 64 + b) * 8 + c] = __float2bfloat16(x[idx]);
}

// ---------------- shared epilogue: bias + relu + bf16 store -----------------
template <int COUT, int MT>
__device__ __forceinline__ void epilogue(f32x4 (&acc)[MT][4], int pos, int mt0,
                                         int q, int nl, const float* bias,
                                         bf16* out_t) {
  const int rowb = q * 4;
#pragma unroll
  for (int ms = 0; ms < MT; ++ms) {
    const int mb = (mt0 + ms) * 16 + rowb;
    if (mb < COUT) {
      const float4 bv = *reinterpret_cast<const float4*>(bias + mb);
#pragma unroll
      for (int t = 0; t < 4; ++t) {
        const int n = t * 16 + nl;
        sh4 s;
#pragma unroll
        for (int r = 0; r < 4; ++r) {
          float vv = acc[ms][t][r] + ((const float*)&bv)[r];
          vv = vv > 0.f ? vv : 0.f;
          bf16 h = __float2bfloat16(vv);
          s[r] = *reinterpret_cast<short*>(&h);
        }
        *reinterpret_cast<sh4*>(out_t + ((size_t)pos * 64 + n) * COUT + mb) = s;
      }
    }
  }
}

// ---------------- L1: division-path sconv (CINW=8 -> shifts), compacted -----
template <int CINW, int COUT, int WIN, int OW, int KTILES, int MT>
__device__ __forceinline__ void sconv_body_div(
    const bf16* __restrict__ in_t, const bf16* __restrict__ wp,
    const float* __restrict__ bias, const int* __restrict__ selh,
    const int* __restrict__ selw, const int* __restrict__ list, int which,
    bf16* __restrict__ out_t) {
  const int bid = blockIdx.x;
  if (bid >= g_cnt[which]) return;
  const int pos = list[bid];
  const int tid = threadIdx.x;
  const int lane = tid & 63;
  const int wv = tid >> 6;
  const int nl = lane & 15;
  const int q = lane >> 4;
  const int mt0 = blockIdx.y * (4 * MT) + wv * MT;
  f32x4 acc[MT][4] = {};
  const int y = pos / OW, xq = pos % OW;
  const int ph = selh[pos] + 2 * y;
  const int pw = selw[pos] + 2 * xq;
  const short8* ap = reinterpret_cast<const short8*>(wp);
#pragma unroll
  for (int kt = 0; kt < KTILES; ++kt) {
    int k = kt * 32 + q * 8;
    int chunk = (int)((unsigned)k / (unsigned)CINW);
    int c = k - chunk * CINW;
    if (chunk > 8) { chunk = 8; c = 0; }
    const int di = (chunk * 342) >> 10;
    const int dj = chunk - di * 3;
    const bf16* bp =
        in_t + ((size_t)((ph + di) * WIN + (pw + dj)) * 64 + nl) * CINW + c;
    short8 Bf[4];
#pragma unroll
    for (int t = 0; t < 4; ++t)
      Bf[t] = *reinterpret_cast<const short8*>(bp + (size_t)t * 16 * CINW);
    short8 Af[MT];
#pragma unroll
    for (int ms = 0; ms < MT; ++ms)
      Af[ms] = ap[((size_t)(mt0 + ms) * KTILES + kt) * 64 + lane];
#pragma unroll
    for (int ms = 0; ms < MT; ++ms)
#pragma unroll
      for (int t = 0; t < 4; ++t)
        acc[ms][t] =
            __builtin_amdgcn_mfma_f32_16x16x32_bf16(Af[ms], Bf[t], acc[ms][t], 0, 0, 0);
  }
  epilogue<COUT, MT>(acc, pos, mt0, q, nl, bias, out_t);
}

// ------------- L2/L3: chunk-outer sconv (no division), compacted ------------
template <int CIN, int SUBT, int COUT, int WIN, int OW, int MT>
__device__ __forceinline__ void sconv_body_pad(
    const bf16* __restrict__ in_t, const bf16* __restrict__ wp,
    const float* __restrict__ bias, const int* __restrict__ selh,
    const int* __restrict__ selw, const int* __restrict__ list, int which,
    bf16* __restrict__ out_t) {
  constexpr int KTILES = 9 * SUBT;
  const int bid = blockIdx.x;
  if (bid >= g_cnt[which]) return;
  const int pos = list[bid];
  const int tid = threadIdx.x;
  const int lane = tid & 63;
  const int wv = tid >> 6;
  const int nl = lane & 15;
  const int q = lane >> 4;
  const int mt0 = blockIdx.y * (4 * MT) + wv * MT;
  f32x4 acc[MT][4] = {};
  const int y = pos / OW, xq = pos % OW;
  const int ph = selh[pos] + 2 * y;
  const int pw = selw[pos] + 2 * xq;
  const int qoff = q * 8;
  const short8* ap = reinterpret_cast<const short8*>(wp);
  for (int chunk = 0; chunk < 9; ++chunk) {
    const int di = (chunk * 342) >> 10;  // chunk/3
    const int dj = chunk - di * 3;
    const bf16* cell =
        in_t + ((size_t)((ph + di) * WIN + (pw + dj)) * 64 + nl) * CIN;
    const short8* aq = ap + ((size_t)chunk * SUBT) * 64 + lane;
#pragma unroll
    for (int cc = 0; cc < SUBT; ++cc) {
      int off;
      if (cc * 32 + 32 <= CIN) {
        off = cc * 32 + qoff;                 // immediate-friendly
      } else {
        int o = cc * 32 + qoff;               // tail: clamp in-bounds
        off = o > (CIN - 8) ? (CIN - 8) : o;  // zero A-weights cover it
      }
      short8 Bf[4];
#pragma unroll
      for (int t = 0; t < 4; ++t)
        Bf[t] = *reinterpret_cast<const short8*>(cell + off + (size_t)t * 16 * CIN);
      short8 Af[MT];
#pragma unroll
      for (int ms = 0; ms < MT; ++ms)
        Af[ms] = aq[((size_t)(mt0 + ms) * KTILES) * 64 + (size_t)cc * 64];
#pragma unroll
      for (int ms = 0; ms < MT; ++ms)
#pragma unroll
        for (int t = 0; t < 4; ++t)
          acc[ms][t] = __builtin_amdgcn_mfma_f32_16x16x32_bf16(Af[ms], Bf[t],
                                                               acc[ms][t], 0, 0, 0);
    }
  }
  epilogue<COUT, MT>(acc, pos, mt0, q, nl, bias, out_t);
}

__global__ __launch_bounds__(256) void k_sconv1(
    const bf16* __restrict__ in_t, const float* __restrict__ bias,
    const int* __restrict__ selh, const int* __restrict__ selw,
    bf16* __restrict__ out_t) {
  sconv_body_div<8, 200, 132, 65, 3, 4>(in_t, g_wp1, bias, selh, selw, g_list1, 0,
                                        out_t);
}
__global__ __launch_bounds__(256) void k_sconv2(
    const bf16* __restrict__ in_t, const float* __restrict__ bias,
    const int* __restrict__ selh, const int* __restrict__ selw,
    bf16* __restrict__ out_t) {
  sconv_body_pad<200, 7, 400, 65, 31, 4>(in_t, g_wp2, bias, selh, selw, g_list2, 1,
                                         out_t);
}
__global__ __launch_bounds__(256) void k_sconv3(
    const bf16* __restrict__ in_t, const float* __restrict__ bias,
    const int* __restrict__ selh, const int* __restrict__ selw,
    bf16* __restrict__ out_t) {
  sconv_body_pad<400, 13, 800, 31, 15, 4>(in_t, g_wp3, bias, selh, selw, g_list3, 2,
                                          out_t);
}

// ---------------- L4: dense 3x3 VALID conv via MFMA, 16-way K-split ---------
__global__ __launch_bounds__(256) void k_conv4m(
    const bf16* __restrict__ in_t,   // [15*15][64][800] bf16
    const float* __restrict__ bias,  // [10] fp32
    float* __restrict__ out) {       // [64][10][13][13] fp32 (pre-zeroed)
  const int pos = blockIdx.x;        // 13*13
  const int y = pos / 13, x = pos % 13;
  const int tid = threadIdx.x;
  const int lane = tid & 63;
  const int wv = tid >> 6;
  const int nl = lane & 15;
  const int q = lane >> 4;
  const int kslice = blockIdx.y * 4 + wv;
  __shared__ f32x4 Racc[4][4][64];
  f32x4 acc[4] = {};
  const short8* ap = reinterpret_cast<const short8*>(g_wp4);
  for (int kt = kslice; kt < 225; kt += 16) {
    const int chunk = kt / 25;  // wave-uniform
    const int c0 = (kt - chunk * 25) * 32;
    const int di = chunk / 3, dj = chunk - di * 3;
    const bf16* bp =
        in_t + ((size_t)((y + di) * 15 + (x + dj)) * 64 + nl) * 800 + c0 + q * 8;
    short8 A0 = ap[(size_t)kt * 64 + lane];
    short8 Bf[4];
#pragma unroll
    for (int t = 0; t < 4; ++t)
      Bf[t] = *reinterpret_cast<const short8*>(bp + (size_t)t * 16 * 800);
#pragma unroll
    for (int t = 0; t < 4; ++t)
      acc[t] = __builtin_amdgcn_mfma_f32_16x16x32_bf16(A0, Bf[t], acc[t], 0, 0, 0);
  }
#pragma unroll
  for (int t = 0; t < 4; ++t) Racc[wv][t][lane] = acc[t];
  __syncthreads();
  if (wv == 0) {
    const int rowb = q * 4;
#pragma unroll
    for (int t = 0; t < 4; ++t) {
      f32x4 s = Racc[0][t][lane];
#pragma unroll
      for (int w2 = 1; w2 < 4; ++w2) {
        f32x4 o = Racc[w2][t][lane];
#pragma unroll
        for (int r = 0; r < 4; ++r) s[r] += o[r];
      }
      const int n = t * 16 + nl;
#pragma unroll
      for (int r = 0; r < 4; ++r) {
        const int m = rowb + r;
        if (m < 10) {
          float v = s[r] + (blockIdx.y == 0 ? bias[m] : 0.f);
          atomicAdd(&out[(((size_t)n * 10 + m) * 13 + y) * 13 + x], v);
        }
      }
    }
  }
}

extern "C" void kernel_launch(void* const* d_in, const int* in_sizes, int n_in,
                              void* d_out, int out_size, void* d_ws, size_t ws_size,
                              hipStream_t stream) {
  const float* x  = (const float*)d_in[0];
  const float* w1 = (const float*)d_in[1];
  const float* b1 = (const float*)d_in[2];
  const float* w2 = (const float*)d_in[3];
  const float* b2 = (const float*)d_in[4];
  const float* w3 = (const float*)d_in[5];
  const float* b3 = (const float*)d_in[6];
  const float* w4 = (const float*)d_in[7];
  const float* b4 = (const float*)d_in[8];
  const int* selh1 = (const int*)d_in[9];
  const int* selw1 = (const int*)d_in[10];
  const int* mask1 = (const int*)d_in[11];
  const int* selh2 = (const int*)d_in[12];
  const int* selw2 = (const int*)d_in[13];
  const int* mask2 = (const int*)d_in[14];
  const int* selh3 = (const int*)d_in[15];
  const int* selw3 = (const int*)d_in[16];
  const int* mask3 = (const int*)d_in[17];

  // ws layout (bytes), total == round-5-proven 157,363,200:
  //   o1t bf16 [65*65][64][200] @ 0            (108,160,000 B; L1 w .. L2 r)
  //   xt  bf16 [132*132][64][8] @ 108,160,000  (17,842,176 B;  fill .. L1 r)
  //   o2t bf16 [31*31][64][400] @ 108,160,000  (49,203,200 B;  L2 w .. L3 r; xt dead)
  //   o3t bf16 [15*15][64][800] @ 0            (23,040,000 B;  L3 w .. L4 r; o1t dead)
  char* ws = (char*)d_ws;
  bf16* o1t = (bf16*)(ws);
  bf16* xt  = (bf16*)(ws + 108160000);
  bf16* o2t = (bf16*)(ws + 108160000);
  bf16* o3t = (bf16*)(ws);

  k_pack1<<<dim3((16 * 3 * 512 + 255) / 256), dim3(256), 0, stream>>>(w1);
  k_pack2<<<dim3((32 * 63 * 512 + 255) / 256), dim3(256), 0, stream>>>(w2);
  k_pack3<<<dim3((64 * 117 * 512 + 255) / 256), dim3(256), 0, stream>>>(w3);
  k_pack4<<<dim3((225 * 512 + 255) / 256), dim3(256), 0, stream>>>(w4);
  k_compact<<<dim3(3), dim3(256), 0, stream>>>(mask1, mask2, mask3);
  k_fill_xt<<<dim3((2230272 + 255) / 256), dim3(256), 0, stream>>>((float*)xt, 2230272);
  k_transpose_x<<<dim3((64 * 3 * 132 * 132 + 255) / 256), dim3(256), 0, stream>>>(x, xt);
  k_zero_out<<<dim3((64 * 10 * 13 * 13 + 255) / 256), dim3(256), 0, stream>>>(
      (float*)d_out);

  // Masked-off positions: relu(bias) fill (cheap, write-only).
  k_fill_off<200><<<dim3(4225), dim3(256), 0, stream>>>(mask1, b1, o1t);
  // L1 (compacted): M-pad 256, grid (4225, 1)
  k_sconv1<<<dim3(4225, 1), dim3(256), 0, stream>>>(xt, b1, selh1, selw1, o1t);

  k_fill_off<400><<<dim3(961), dim3(256), 0, stream>>>(mask2, b2, o2t);
  // L2 (compacted): M-pad 512, grid (961, 2)
  k_sconv2<<<dim3(961, 2), dim3(256), 0, stream>>>(o1t, b2, selh2, selw2, o2t);

  k_fill_off<800><<<dim3(225), dim3(256), 0, stream>>>(mask3, b3, o3t);
  // L3 (compacted): M-pad 1024, grid (225, 4)
  k_sconv3<<<dim3(225, 4), dim3(256), 0, stream>>>(o2t, b3, selh3, selw3, o3t);

  // L4: 16-way K-split, atomic accumulate
  k_conv4m<<<dim3(13 * 13, 4), dim3(256), 0, stream>>>(o3t, b4, (float*)d_out);
}

// Round 12
// 565.280 us; speedup vs baseline: 1.1598x; 1.1533x over previous
//
#include <hip/hip_runtime.h>
#include <hip/hip_bf16.h>

using bf16 = __hip_bfloat16;
using short8 = __attribute__((ext_vector_type(8))) short;
using sh4 = __attribute__((ext_vector_type(4))) short;
using f32x4 = __attribute__((ext_vector_type(4))) float;

// Pre-packed A-operand (weights) in MFMA 16x16x32 frag order, module-scope.
// L1 (div path): k = kt*32+(lane>>4)*8+j -> chunk=k/8, c=k%8.
// L2/L3 (chunk-padded path): kt = chunk*SUBT+cc, c = cc*32+(lane>>4)*8+j,
//   weight nonzero iff c < CIN  (tail B reads are clamped in-bounds x zero A).
__device__ __align__(16) bf16 g_wp1[16 * 3 * 512];    //  48 KB (M 256, KT 3)
__device__ __align__(16) bf16 g_wp2[32 * 63 * 512];   // 2.1 MB (M 512, KT 63 = 9*7)
__device__ __align__(16) bf16 g_wp3[64 * 117 * 512];  // 7.7 MB (M 1024, KT 117 = 9*13)
__device__ __align__(16) bf16 g_wp4[1 * 225 * 512];   // 231 KB (M 16, KT 225 exact)

// Compacted masked-on position lists (order-preserving -> spatial locality).
__device__ int g_list1[4225];
__device__ int g_list2[961];
__device__ int g_list3[225];
__device__ int g_cnt[3];

// ---------------- weight packs ----------------
__global__ __launch_bounds__(256) void k_pack1(const float* __restrict__ w) {
  int el = blockIdx.x * 256 + threadIdx.x;
  if (el >= 16 * 3 * 512) return;
  int j = el & 7, lane = (el >> 3) & 63, rest = el >> 9;
  int kt = rest % 3, mt = rest / 3;
  int m = mt * 16 + (lane & 15);
  int k = kt * 32 + ((lane >> 4) * 8) + j;
  int chunk = k >> 3, c = k & 7;
  float val = 0.f;
  if (m < 200 && chunk < 9 && c < 3) val = w[((size_t)m * 3 + c) * 9 + chunk];
  g_wp1[el] = __float2bfloat16(val);
}
template <int CIN, int SUBT, int COUT>
__device__ __forceinline__ void pack_pad(const float* __restrict__ w,
                                         bf16* __restrict__ dst, int total) {
  int el = blockIdx.x * 256 + threadIdx.x;
  if (el >= total) return;
  int j = el & 7, lane = (el >> 3) & 63, rest = el >> 9;
  int kt = rest % (9 * SUBT), mt = rest / (9 * SUBT);
  int chunk = kt / SUBT, cc = kt - chunk * SUBT;
  int m = mt * 16 + (lane & 15);
  int c = cc * 32 + ((lane >> 4) * 8) + j;
  float val = 0.f;
  if (m < COUT && c < CIN) val = w[((size_t)m * CIN + c) * 9 + chunk];
  dst[el] = __float2bfloat16(val);
}
__global__ __launch_bounds__(256) void k_pack2(const float* __restrict__ w) {
  pack_pad<200, 7, 400>(w, g_wp2, 32 * 63 * 512);
}
__global__ __launch_bounds__(256) void k_pack3(const float* __restrict__ w) {
  pack_pad<400, 13, 800>(w, g_wp3, 64 * 117 * 512);
}
__global__ __launch_bounds__(256) void k_pack4(const float* __restrict__ w) {
  pack_pad<800, 25, 10>(w, g_wp4, 225 * 512);
}

// -------- mask compaction, ORDER-PRESERVING (block scan, 1 block/list) ------
__global__ __launch_bounds__(256) void k_compact(const int* __restrict__ m1,
                                                 const int* __restrict__ m2,
                                                 const int* __restrict__ m3) {
  const int which = blockIdx.x;
  const int* m = which == 0 ? m1 : (which == 1 ? m2 : m3);
  int* lst = which == 0 ? g_list1 : (which == 1 ? g_list2 : g_list3);
  const int n = which == 0 ? 4225 : (which == 1 ? 961 : 225);
  const int per = (n + 255) / 256;
  const int lo = threadIdx.x * per;
  const int hi = lo + per < n ? lo + per : n;
  __shared__ int cnt[256];
  __shared__ int off[256];
  int c = 0;
  for (int i = lo; i < hi; ++i) c += (m[i] != 0);
  cnt[threadIdx.x] = c;
  __syncthreads();
  if (threadIdx.x == 0) {
    int s = 0;
    for (int t = 0; t < 256; ++t) { off[t] = s; s += cnt[t]; }
    g_cnt[which] = s;
  }
  __syncthreads();
  int o = off[threadIdx.x];
  for (int i = lo; i < hi; ++i)
    if (m[i] != 0) lst[o++] = i;
}

// Fill masked-OFF positions with relu(bias) (reference: where(mask,conv,0)+bias).
template <int COUT>
__global__ __launch_bounds__(256) void k_fill_off(const int* __restrict__ mask,
                                                  const float* __restrict__ bias,
                                                  bf16* __restrict__ out_t) {
  const int pos = blockIdx.x;
  if (mask[pos] != 0) return;
  bf16* base = out_t + (size_t)pos * 64 * COUT;
  for (int idx = threadIdx.x; idx < 64 * COUT / 8; idx += 256) {
    const int c0 = (idx * 8) % COUT;
    short8 s;
#pragma unroll
    for (int j = 0; j < 8; ++j) {
      float v = bias[c0 + j];
      v = v > 0.f ? v : 0.f;
      bf16 h = __float2bfloat16(v);
      s[j] = *reinterpret_cast<short*>(&h);
    }
    *reinterpret_cast<short8*>(base + (size_t)idx * 8) = s;
  }
}

// zero-fill xt (pad channels 3..7 must be 0)
__global__ __launch_bounds__(256) void k_fill_xt(float* __restrict__ p, int n4) {
  int i = blockIdx.x * 256 + threadIdx.x;
  if (i < n4) reinterpret_cast<float4*>(p)[i] = float4{0.f, 0.f, 0.f, 0.f};
}
// zero-fill d_out (conv4m accumulates with atomics)
__global__ __launch_bounds__(256) void k_zero_out(float* __restrict__ p) {
  int i = blockIdx.x * 256 + threadIdx.x;
  if (i < 64 * 10 * 13 * 13) p[i] = 0.f;
}

// x: [64][3][132][132] fp32 -> xt: [132*132][64][8] bf16 (c innermost, 8-pad)
__global__ __launch_bounds__(256) void k_transpose_x(const float* __restrict__ x,
                                                     bf16* __restrict__ xt) {
  int idx = blockIdx.x * 256 + threadIdx.x;
  constexpr int N = 64 * 3 * 132 * 132;
  if (idx >= N) return;
  int w = idx % 132;
  int t = idx / 132;
  int h = t % 132;
  t /= 132;
  int c = t % 3;
  int b = t / 3;
  xt[((size_t)(h * 132 + w) * 64 + b) * 8 + c] = __float2bfloat16(x[idx]);
}

// ---------------- shared epilogue: bias + relu + bf16 store -----------------
template <int COUT, int MT>
__device__ __forceinline__ void epilogue(f32x4 (&acc)[MT][4], int pos, int mt0,
                                         int q, int nl, const float* bias,
                                         bf16* out_t) {
  const int rowb = q * 4;
#pragma unroll
  for (int ms = 0; ms < MT; ++ms) {
    const int mb = (mt0 + ms) * 16 + rowb;
    if (mb < COUT) {
      const float4 bv = *reinterpret_cast<const float4*>(bias + mb);
#pragma unroll
      for (int t = 0; t < 4; ++t) {
        const int n = t * 16 + nl;
        sh4 s;
#pragma unroll
        for (int r = 0; r < 4; ++r) {
          float vv = acc[ms][t][r] + ((const float*)&bv)[r];
          vv = vv > 0.f ? vv : 0.f;
          bf16 h = __float2bfloat16(vv);
          s[r] = *reinterpret_cast<short*>(&h);
        }
        *reinterpret_cast<sh4*>(out_t + ((size_t)pos * 64 + n) * COUT + mb) = s;
      }
    }
  }
}

// ---------------- L1: division-path sconv (CINW=8 -> shifts), compacted -----
template <int CINW, int COUT, int WIN, int OW, int KTILES, int MT>
__device__ __forceinline__ void sconv_body_div(
    const bf16* __restrict__ in_t, const bf16* __restrict__ wp,
    const float* __restrict__ bias, const int* __restrict__ selh,
    const int* __restrict__ selw, const int* __restrict__ list, int which,
    bf16* __restrict__ out_t) {
  const int bid = blockIdx.x;
  if (bid >= g_cnt[which]) return;
  const int pos = list[bid];
  const int tid = threadIdx.x;
  const int lane = tid & 63;
  const int wv = tid >> 6;
  const int nl = lane & 15;
  const int q = lane >> 4;
  const int mt0 = blockIdx.y * (4 * MT) + wv * MT;
  f32x4 acc[MT][4] = {};
  const int y = pos / OW, xq = pos % OW;
  const int ph = selh[pos] + 2 * y;
  const int pw = selw[pos] + 2 * xq;
  const short8* ap = reinterpret_cast<const short8*>(wp);
#pragma unroll
  for (int kt = 0; kt < KTILES; ++kt) {
    int k = kt * 32 + q * 8;
    int chunk = (int)((unsigned)k / (unsigned)CINW);
    int c = k - chunk * CINW;
    if (chunk > 8) { chunk = 8; c = 0; }
    const int di = (chunk * 342) >> 10;
    const int dj = chunk - di * 3;
    const bf16* bp =
        in_t + ((size_t)((ph + di) * WIN + (pw + dj)) * 64 + nl) * CINW + c;
    short8 Bf[4];
#pragma unroll
    for (int t = 0; t < 4; ++t)
      Bf[t] = *reinterpret_cast<const short8*>(bp + (size_t)t * 16 * CINW);
    short8 Af[MT];
#pragma unroll
    for (int ms = 0; ms < MT; ++ms)
      Af[ms] = ap[((size_t)(mt0 + ms) * KTILES + kt) * 64 + lane];
#pragma unroll
    for (int ms = 0; ms < MT; ++ms)
#pragma unroll
      for (int t = 0; t < 4; ++t)
        acc[ms][t] =
            __builtin_amdgcn_mfma_f32_16x16x32_bf16(Af[ms], Bf[t], acc[ms][t], 0, 0, 0);
  }
  epilogue<COUT, MT>(acc, pos, mt0, q, nl, bias, out_t);
}

// ------------- L2/L3: chunk-outer sconv (no division), compacted, MT=8 ------
template <int CIN, int SUBT, int COUT, int WIN, int OW, int MT>
__device__ __forceinline__ void sconv_body_pad(
    const bf16* __restrict__ in_t, const bf16* __restrict__ wp,
    const float* __restrict__ bias, const int* __restrict__ selh,
    const int* __restrict__ selw, const int* __restrict__ list, int which,
    bf16* __restrict__ out_t) {
  constexpr int KTILES = 9 * SUBT;
  const int bid = blockIdx.x;
  if (bid >= g_cnt[which]) return;
  const int pos = list[bid];
  const int tid = threadIdx.x;
  const int lane = tid & 63;
  const int wv = tid >> 6;
  const int nl = lane & 15;
  const int q = lane >> 4;
  const int mt0 = blockIdx.y * (4 * MT) + wv * MT;
  f32x4 acc[MT][4] = {};
  const int y = pos / OW, xq = pos % OW;
  const int ph = selh[pos] + 2 * y;
  const int pw = selw[pos] + 2 * xq;
  const int qoff = q * 8;
  const short8* ap = reinterpret_cast<const short8*>(wp);
  for (int chunk = 0; chunk < 9; ++chunk) {
    const int di = (chunk * 342) >> 10;  // chunk/3
    const int dj = chunk - di * 3;
    const bf16* cell =
        in_t + ((size_t)((ph + di) * WIN + (pw + dj)) * 64 + nl) * CIN;
    const short8* aq = ap + ((size_t)chunk * SUBT) * 64 + lane;
#pragma unroll
    for (int cc = 0; cc < SUBT; ++cc) {
      int off;
      if (cc * 32 + 32 <= CIN) {
        off = cc * 32 + qoff;                 // immediate-friendly
      } else {
        int o = cc * 32 + qoff;               // tail: clamp in-bounds
        off = o > (CIN - 8) ? (CIN - 8) : o;  // zero A-weights cover it
      }
      short8 Bf[4];
#pragma unroll
      for (int t = 0; t < 4; ++t)
        Bf[t] = *reinterpret_cast<const short8*>(cell + off + (size_t)t * 16 * CIN);
      short8 Af[MT];
#pragma unroll
      for (int ms = 0; ms < MT; ++ms)
        Af[ms] = aq[((size_t)(mt0 + ms) * KTILES) * 64 + (size_t)cc * 64];
#pragma unroll
      for (int ms = 0; ms < MT; ++ms)
#pragma unroll
        for (int t = 0; t < 4; ++t)
          acc[ms][t] = __builtin_amdgcn_mfma_f32_16x16x32_bf16(Af[ms], Bf[t],
                                                               acc[ms][t], 0, 0, 0);
    }
  }
  epilogue<COUT, MT>(acc, pos, mt0, q, nl, bias, out_t);
}

__global__ __launch_bounds__(256) void k_sconv1(
    const bf16* __restrict__ in_t, const float* __restrict__ bias,
    const int* __restrict__ selh, const int* __restrict__ selw,
    bf16* __restrict__ out_t) {
  sconv_body_div<8, 200, 132, 65, 3, 4>(in_t, g_wp1, bias, selh, selw, g_list1, 0,
                                        out_t);
}
// MT=8: M=128/wave, 512/block -> L2 in one block/position (grid.y=1).
__global__ __launch_bounds__(256, 2) void k_sconv2(
    const bf16* __restrict__ in_t, const float* __restrict__ bias,
    const int* __restrict__ selh, const int* __restrict__ selw,
    bf16* __restrict__ out_t) {
  sconv_body_pad<200, 7, 400, 65, 31, 8>(in_t, g_wp2, bias, selh, selw, g_list2, 1,
                                         out_t);
}
__global__ __launch_bounds__(256, 2) void k_sconv3(
    const bf16* __restrict__ in_t, const float* __restrict__ bias,
    const int* __restrict__ selh, const int* __restrict__ selw,
    bf16* __restrict__ out_t) {
  sconv_body_pad<400, 13, 800, 31, 15, 8>(in_t, g_wp3, bias, selh, selw, g_list3, 2,
                                          out_t);
}

// ---------------- L4: dense 3x3 VALID conv via MFMA, 16-way K-split ---------
__global__ __launch_bounds__(256) void k_conv4m(
    const bf16* __restrict__ in_t,   // [15*15][64][800] bf16
    const float* __restrict__ bias,  // [10] fp32
    float* __restrict__ out) {       // [64][10][13][13] fp32 (pre-zeroed)
  const int pos = blockIdx.x;        // 13*13
  const int y = pos / 13, x = pos % 13;
  const int tid = threadIdx.x;
  const int lane = tid & 63;
  const int wv = tid >> 6;
  const int nl = lane & 15;
  const int q = lane >> 4;
  const int kslice = blockIdx.y * 4 + wv;
  __shared__ f32x4 Racc[4][4][64];
  f32x4 acc[4] = {};
  const short8* ap = reinterpret_cast<const short8*>(g_wp4);
  for (int kt = kslice; kt < 225; kt += 16) {
    const int chunk = kt / 25;  // wave-uniform
    const int c0 = (kt - chunk * 25) * 32;
    const int di = chunk / 3, dj = chunk - di * 3;
    const bf16* bp =
        in_t + ((size_t)((y + di) * 15 + (x + dj)) * 64 + nl) * 800 + c0 + q * 8;
    short8 A0 = ap[(size_t)kt * 64 + lane];
    short8 Bf[4];
#pragma unroll
    for (int t = 0; t < 4; ++t)
      Bf[t] = *reinterpret_cast<const short8*>(bp + (size_t)t * 16 * 800);
#pragma unroll
    for (int t = 0; t < 4; ++t)
      acc[t] = __builtin_amdgcn_mfma_f32_16x16x32_bf16(A0, Bf[t], acc[t], 0, 0, 0);
  }
#pragma unroll
  for (int t = 0; t < 4; ++t) Racc[wv][t][lane] = acc[t];
  __syncthreads();
  if (wv == 0) {
    const int rowb = q * 4;
#pragma unroll
    for (int t = 0; t < 4; ++t) {
      f32x4 s = Racc[0][t][lane];
#pragma unroll
      for (int w2 = 1; w2 < 4; ++w2) {
        f32x4 o = Racc[w2][t][lane];
#pragma unroll
        for (int r = 0; r < 4; ++r) s[r] += o[r];
      }
      const int n = t * 16 + nl;
#pragma unroll
      for (int r = 0; r < 4; ++r) {
        const int m = rowb + r;
        if (m < 10) {
          float v = s[r] + (blockIdx.y == 0 ? bias[m] : 0.f);
          atomicAdd(&out[(((size_t)n * 10 + m) * 13 + y) * 13 + x], v);
        }
      }
    }
  }
}

extern "C" void kernel_launch(void* const* d_in, const int* in_sizes, int n_in,
                              void* d_out, int out_size, void* d_ws, size_t ws_size,
                              hipStream_t stream) {
  const float* x  = (const float*)d_in[0];
  const float* w1 = (const float*)d_in[1];
  const float* b1 = (const float*)d_in[2];
  const float* w2 = (const float*)d_in[3];
  const float* b2 = (const float*)d_in[4];
  const float* w3 = (const float*)d_in[5];
  const float* b3 = (const float*)d_in[6];
  const float* w4 = (const float*)d_in[7];
  const float* b4 = (const float*)d_in[8];
  const int* selh1 = (const int*)d_in[9];
  const int* selw1 = (const int*)d_in[10];
  const int* mask1 = (const int*)d_in[11];
  const int* selh2 = (const int*)d_in[12];
  const int* selw2 = (const int*)d_in[13];
  const int* mask2 = (const int*)d_in[14];
  const int* selh3 = (const int*)d_in[15];
  const int* selw3 = (const int*)d_in[16];
  const int* mask3 = (const int*)d_in[17];

  // ws layout (bytes), total == round-5-proven 157,363,200:
  //   o1t bf16 [65*65][64][200] @ 0            (108,160,000 B; L1 w .. L2 r)
  //   xt  bf16 [132*132][64][8] @ 108,160,000  (17,842,176 B;  fill .. L1 r)
  //   o2t bf16 [31*31][64][400] @ 108,160,000  (49,203,200 B;  L2 w .. L3 r; xt dead)
  //   o3t bf16 [15*15][64][800] @ 0            (23,040,000 B;  L3 w .. L4 r; o1t dead)
  char* ws = (char*)d_ws;
  bf16* o1t = (bf16*)(ws);
  bf16* xt  = (bf16*)(ws + 108160000);
  bf16* o2t = (bf16*)(ws + 108160000);
  bf16* o3t = (bf16*)(ws);

  k_pack1<<<dim3((16 * 3 * 512 + 255) / 256), dim3(256), 0, stream>>>(w1);
  k_pack2<<<dim3((32 * 63 * 512 + 255) / 256), dim3(256), 0, stream>>>(w2);
  k_pack3<<<dim3((64 * 117 * 512 + 255) / 256), dim3(256), 0, stream>>>(w3);
  k_pack4<<<dim3((225 * 512 + 255) / 256), dim3(256), 0, stream>>>(w4);
  k_compact<<<dim3(3), dim3(256), 0, stream>>>(mask1, mask2, mask3);
  k_fill_xt<<<dim3((2230272 + 255) / 256), dim3(256), 0, stream>>>((float*)xt, 2230272);
  k_transpose_x<<<dim3((64 * 3 * 132 * 132 + 255) / 256), dim3(256), 0, stream>>>(x, xt);
  k_zero_out<<<dim3((64 * 10 * 13 * 13 + 255) / 256), dim3(256), 0, stream>>>(
      (float*)d_out);

  // Masked-off positions: relu(bias) fill (cheap, write-only).
  k_fill_off<200><<<dim3(4225), dim3(256), 0, stream>>>(mask1, b1, o1t);
  // L1 (compacted): M-pad 256, grid (4225, 1)
  k_sconv1<<<dim3(4225, 1), dim3(256), 0, stream>>>(xt, b1, selh1, selw1, o1t);

  k_fill_off<400><<<dim3(961), dim3(256), 0, stream>>>(mask2, b2, o2t);
  // L2 (compacted): M-pad 512, one block/position, grid (961, 1)
  k_sconv2<<<dim3(961, 1), dim3(256), 0, stream>>>(o1t, b2, selh2, selw2, o2t);

  k_fill_off<800><<<dim3(225), dim3(256), 0, stream>>>(mask3, b3, o3t);
  // L3 (compacted): M-pad 1024, grid (225, 2)
  k_sconv3<<<dim3(225, 2), dim3(256), 0, stream>>>(o2t, b3, selh3, selw3, o3t);

  // L4: 16-way K-split, atomic accumulate
  k_conv4m<<<dim3(13 * 13, 4), dim3(256), 0, stream>>>(o3t, b4, (float*)d_out);
}